// Round 8
// baseline (507.569 us; speedup 1.0000x reference)
//
#include <hip/hip_runtime.h>
#include <hip/hip_fp16.h>

// ScaledDotProductAttention: context = softmax(QK^T/sqrt(d) - 100*mask) @ V
// B=32 Tq=2048 Tk=1024 d=128 dv=256, fp32 in/out.
// R8: DRAM-row-locality restructure. Every HBM stream is a per-wave
// CONTIGUOUS row sweep (>=1KB/instr, monotone): mask read, e write, e read,
// score write, ctx write. Strided fragment traffic (K16, VT) stays in L2.
//   k1: QK^T (K16 frags from L2) -> logits LDS -> row-sweep mask+exp ->
//       e (f16, contiguous) into score slots + 1/rowsum -> ws.
//   k2: row-sweep e -> score (contiguous, x inv) + e -> LDS P; PV MFMA
//       (P LDS x VT L2); ctx via LDS transpose -> contiguous sweeps.

namespace {

constexpr int kB = 32, kTq = 2048, kTk = 1024, kD = 128, kDv = 256;
constexpr float kScale = 0.08838834764831845f;  // 1/sqrt(128)

typedef _Float16 half8 __attribute__((ext_vector_type(8)));
typedef _Float16 half4 __attribute__((ext_vector_type(4)));
typedef float    f32x4 __attribute__((ext_vector_type(4)));

// workspace layout (25.4 MB)
constexpr size_t kWsK   = 0;          // K16 [32][1024][128] f16 = 8 MiB
constexpr size_t kWsV   = 8388608;    // VT  [32][256][1024] f16 = 16 MiB
constexpr size_t kWsInv = 25165824;   // inv rowsum [32*2048] f32 = 256 KiB

__device__ __forceinline__ int pswz(int row, int cb) {  // row<32, cb<2048 bytes
  return row * 2048 + (cb ^ ((row & 7) << 4));
}

struct Frag4 { half8 a, b, c, d; };

// ---- pre-kernel 1: K f32 -> f16 ----
__global__ __launch_bounds__(256)
void cvt_k(const float* __restrict__ in, _Float16* __restrict__ out) {
  int i = (blockIdx.x * 256 + threadIdx.x) * 8;
  f32x4 a = *(const f32x4*)(in + i);
  f32x4 b = *(const f32x4*)(in + i + 4);
  half8 h;
  h[0] = a[0]; h[1] = a[1]; h[2] = a[2]; h[3] = a[3];
  h[4] = b[0]; h[5] = b[1]; h[6] = b[2]; h[7] = b[3];
  *(half8*)(out + i) = h;
}

// ---- pre-kernel 2: V [k][dv] f32 -> V^T [dv][k] f16 ----
__global__ __launch_bounds__(256)
void trans_v(const float* __restrict__ v, _Float16* __restrict__ vt) {
  __shared__ _Float16 t[64 * 66];
  const int b   = blockIdx.x >> 6;
  const int idx = blockIdx.x & 63;
  const int k0  = (idx & 15) * 64;
  const int d0  = (idx >> 4) * 64;
  const int r = threadIdx.x >> 6, c = threadIdx.x & 63;
#pragma unroll 4
  for (int it = 0; it < 16; ++it) {
    float x = v[((size_t)b * kTk + k0 + it * 4 + r) * kDv + d0 + c];
    t[c * 66 + it * 4 + r] = (_Float16)x;
  }
  __syncthreads();
  const int dr = threadIdx.x >> 4, kc = (threadIdx.x & 15) * 4;
#pragma unroll
  for (int it = 0; it < 4; ++it) {
    int drow = it * 16 + dr;
    half4 h;
#pragma unroll
    for (int j = 0; j < 4; ++j) h[j] = t[drow * 66 + kc + j];
    *(half4*)(vt + ((size_t)b * kDv + d0 + drow) * kTk + k0 + kc) = h;
  }
}

// ---- K1: QK^T -> logits(LDS) -> mask sweep + exp -> e + 1/rowsum ----
__global__ __launch_bounds__(512, 4)
void k1_logits(const float* __restrict__ qg, const _Float16* __restrict__ K16,
               const float* __restrict__ mg, float* __restrict__ out,
               float* __restrict__ inv_ws) {
  __shared__ __align__(16) unsigned char s_[65536];

  const int tid  = threadIdx.x;
  const int lane = tid & 63;
  const int wid  = tid >> 6;     // 0..7
  const int l15  = lane & 15;
  const int lg   = lane >> 4;    // 0..3

  const int bi    = blockIdx.x;               // 0..2047
  const int batch = (bi & 7) * 4 + (bi >> 9); // XCD-grouped
  const int q0    = ((bi >> 3) & 63) * 32;

  const float* Q = qg + ((size_t)batch * kTq + q0) * kD;
  const _Float16* Kb = K16 + (size_t)batch * kTk * kD;
  const float* M = mg + ((size_t)batch * kTq + q0) * kTk;
  char* Ebase = (char*)(out + (size_t)kB * kTq * kDv) +
                ((size_t)batch * kTq + q0) * 4096;

  // ===== Phase A: QK^T -> logits*scale f16 in LDS (R6-proven) =====
  const int wr = wid >> 2;   // 0..1 : q rows 16*wr..+15
  const int wc = wid & 3;    // 0..3 : keys wc*16.. within each 64-key step
  half8 qf[4];
  {
    const float* qrow = Q + (size_t)(wr * 16 + l15) * kD + lg * 8;
#pragma unroll
    for (int c = 0; c < 4; ++c) {
      f32x4 a = *(const f32x4*)(qrow + c * 32);
      f32x4 b = *(const f32x4*)(qrow + c * 32 + 4);
      half8 h;
      h[0] = a[0]; h[1] = a[1]; h[2] = a[2]; h[3] = a[3];
      h[4] = b[0]; h[5] = b[1]; h[6] = b[2]; h[7] = b[3];
      qf[c] = h;
    }
  }
  auto ldK = [&](int s, half8* f) {
    const _Float16* p = Kb + (size_t)(s * 64 + wc * 16 + l15) * kD + lg * 8;
    f[0] = *(const half8*)(p);
    f[1] = *(const half8*)(p + 32);
    f[2] = *(const half8*)(p + 64);
    f[3] = *(const half8*)(p + 96);
  };
  auto qk = [&](const half8* f) -> f32x4 {
    f32x4 acc = {0.f, 0.f, 0.f, 0.f};
    acc = __builtin_amdgcn_mfma_f32_16x16x32_f16(qf[0], f[0], acc, 0, 0, 0);
    acc = __builtin_amdgcn_mfma_f32_16x16x32_f16(qf[1], f[1], acc, 0, 0, 0);
    acc = __builtin_amdgcn_mfma_f32_16x16x32_f16(qf[2], f[2], acc, 0, 0, 0);
    acc = __builtin_amdgcn_mfma_f32_16x16x32_f16(qf[3], f[3], acc, 0, 0, 0);
    return acc;
  };
  auto stP = [&](f32x4 acc, int s) {
    int colb = (s * 64 + wc * 16 + l15) * 2;
#pragma unroll
    for (int j = 0; j < 4; ++j)
      *(_Float16*)(s_ + pswz(wr * 16 + lg * 4 + j, colb)) =
          (_Float16)(acc[j] * kScale);
  };
  half8 fA[4], fB[4];
  ldK(0, fA); ldK(1, fB);
  for (int s = 0; s < 16; s += 2) {
    __builtin_amdgcn_s_setprio(1);
    f32x4 a0 = qk(fA);
    __builtin_amdgcn_s_setprio(0);
    if (s + 2 < 16) ldK(s + 2, fA);
    stP(a0, s);
    __builtin_amdgcn_s_setprio(1);
    f32x4 a1 = qk(fB);
    __builtin_amdgcn_s_setprio(0);
    if (s + 3 < 16) ldK(s + 3, fB);
    stP(a1, s + 1);
  }
  __syncthreads();

  // ===== Phase B: per-wave contiguous row sweeps =====
  // wave wid owns rows wid*4..+3. Per (row, half): mask read = 2 f32x4
  // (instr pair covers contiguous 2KB), e write = 1 half8 (1KB contiguous).
  const int r0 = wid * 4;
  f32x4 cA = *(const f32x4*)(M + (size_t)r0 * kTk + lane * 8);
  f32x4 cB = *(const f32x4*)(M + (size_t)r0 * kTk + lane * 8 + 4);
  f32x4 nA, nB;
  float rs = 0.f;
#pragma unroll
  for (int it = 0; it < 8; ++it) {
    const int r = r0 + (it >> 1), h = it & 1;
    if (it < 7) {
      const int rn = r0 + ((it + 1) >> 1), hn = (it + 1) & 1;
      nA = *(const f32x4*)(M + (size_t)rn * kTk + hn * 512 + lane * 8);
      nB = *(const f32x4*)(M + (size_t)rn * kTk + hn * 512 + lane * 8 + 4);
    }
    half8 sv = *(const half8*)(s_ + pswz(r, h * 1024 + lane * 16));
    float e0 = __expf((float)sv[0] - 100.f * cA[0]);
    float e1 = __expf((float)sv[1] - 100.f * cA[1]);
    float e2 = __expf((float)sv[2] - 100.f * cA[2]);
    float e3 = __expf((float)sv[3] - 100.f * cA[3]);
    float e4 = __expf((float)sv[4] - 100.f * cB[0]);
    float e5 = __expf((float)sv[5] - 100.f * cB[1]);
    float e6 = __expf((float)sv[6] - 100.f * cB[2]);
    float e7 = __expf((float)sv[7] - 100.f * cB[3]);
    rs += ((e0 + e1) + (e2 + e3)) + ((e4 + e5) + (e6 + e7));
    half8 ev;
    ev[0] = e0; ev[1] = e1; ev[2] = e2; ev[3] = e3;
    ev[4] = e4; ev[5] = e5; ev[6] = e6; ev[7] = e7;
    *(half8*)(Ebase + (size_t)r * 4096 + h * 1024 + lane * 16) = ev;
    if (h == 1) {   // full row done -> 64-lane reduce -> inv
      rs += __shfl_xor(rs, 1);  rs += __shfl_xor(rs, 2);
      rs += __shfl_xor(rs, 4);  rs += __shfl_xor(rs, 8);
      rs += __shfl_xor(rs, 16); rs += __shfl_xor(rs, 32);
      if (lane == 0) inv_ws[(size_t)batch * kTq + q0 + r] = 1.0f / rs;
      rs = 0.f;
    }
    cA = nA; cB = nB;
  }
}

// ---- K2: e sweep -> score + LDS P; PV MFMA; ctx via LDS transpose ----
__global__ __launch_bounds__(512, 4)
void k2_pv(const _Float16* __restrict__ VT, const float* __restrict__ inv_ws,
           float* __restrict__ out) {
  __shared__ __align__(16) unsigned char s_[65536];

  const int tid  = threadIdx.x;
  const int lane = tid & 63;
  const int wid  = tid >> 6;     // 0..7
  const int l15  = lane & 15;
  const int lg   = lane >> 4;    // 0..3

  const int bi    = blockIdx.x;
  const int batch = (bi & 7) * 4 + (bi >> 9);
  const int q0    = ((bi >> 3) & 63) * 32;

  float* CTX = out + ((size_t)batch * kTq + q0) * kDv;
  float* SCR = out + (size_t)kB * kTq * kDv + ((size_t)batch * kTq + q0) * kTk;
  const char* Ebase = (const char*)SCR;   // e f16 in first 2KB of each 4KB slot
  const _Float16* Vb = VT + (size_t)batch * kDv * kTk;
  const float* INV = inv_ws + (size_t)batch * kTq + q0;

  const int r0 = wid * 4;
  f32x4 iv = *(const f32x4*)(INV + r0);   // broadcast: 4 row reciprocals

  // ===== Phase A: per-wave contiguous sweeps: e -> score + LDS P =====
  // Order h=1 before h=0 so score writes never clobber unread e bytes:
  //   h=1: e=[1024,2048) read, score writes [2048,4096)  (disjoint)
  //   h=0: e=[0,1024) read (waited via dataflow), score writes [0,2048)
  half8 evc, evn;
  evc = *(const half8*)(Ebase + (size_t)r0 * 4096 + 1024 + lane * 16);
#pragma unroll
  for (int it = 0; it < 8; ++it) {
    const int r = r0 + (it >> 1), h = 1 - (it & 1);
    if (it < 7) {
      const int rn = r0 + ((it + 1) >> 1), hn = 1 - ((it + 1) & 1);
      evn = *(const half8*)(Ebase + (size_t)rn * 4096 + hn * 1024 + lane * 16);
    }
    const float inv = iv[it >> 1];
    f32x4 oA, oB;
    oA[0] = (float)evc[0] * inv; oA[1] = (float)evc[1] * inv;
    oA[2] = (float)evc[2] * inv; oA[3] = (float)evc[3] * inv;
    oB[0] = (float)evc[4] * inv; oB[1] = (float)evc[5] * inv;
    oB[2] = (float)evc[6] * inv; oB[3] = (float)evc[7] * inv;
    *(f32x4*)(SCR + (size_t)r * kTk + h * 512 + lane * 8)     = oA;
    *(f32x4*)(SCR + (size_t)r * kTk + h * 512 + lane * 8 + 4) = oB;
    *(half8*)(s_ + pswz(r, h * 1024 + lane * 16)) = evc;   // P tile (e)
    evc = evn;
  }
  __syncthreads();

  // ===== Phase B: PV = P(LDS) x VT(L2), 2-deep =====
  const int wr = wid >> 2;   // 0..1 : q rows 16*wr..+15
  const int wc = wid & 3;    // 0..3 : dv cols wc*64..+63
  auto ldP = [&](int kc) -> half8 {
    return *(const half8*)(s_ + pswz(wr * 16 + l15, kc * 64 + lg * 16));
  };
  auto ldV = [&](int kc) -> Frag4 {
    const _Float16* p = Vb + (size_t)(wc * 64 + l15) * kTk + kc * 32 + lg * 8;
    Frag4 f;
    f.a = *(const half8*)(p);
    f.b = *(const half8*)(p + (size_t)16 * kTk);
    f.c = *(const half8*)(p + (size_t)32 * kTk);
    f.d = *(const half8*)(p + (size_t)48 * kTk);
    return f;
  };
  f32x4 c0 = {0,0,0,0}, c1 = {0,0,0,0}, c2 = {0,0,0,0}, c3 = {0,0,0,0};
  half8 pA = ldP(0); Frag4 vA = ldV(0);
  half8 pB = ldP(1); Frag4 vB = ldV(1);
  for (int kc = 0; kc < 32; kc += 2) {
    __builtin_amdgcn_s_setprio(1);
    c0 = __builtin_amdgcn_mfma_f32_16x16x32_f16(pA, vA.a, c0, 0, 0, 0);
    c1 = __builtin_amdgcn_mfma_f32_16x16x32_f16(pA, vA.b, c1, 0, 0, 0);
    c2 = __builtin_amdgcn_mfma_f32_16x16x32_f16(pA, vA.c, c2, 0, 0, 0);
    c3 = __builtin_amdgcn_mfma_f32_16x16x32_f16(pA, vA.d, c3, 0, 0, 0);
    __builtin_amdgcn_s_setprio(0);
    if (kc + 2 < 32) { pA = ldP(kc + 2); vA = ldV(kc + 2); }
    __builtin_amdgcn_s_setprio(1);
    c0 = __builtin_amdgcn_mfma_f32_16x16x32_f16(pB, vB.a, c0, 0, 0, 0);
    c1 = __builtin_amdgcn_mfma_f32_16x16x32_f16(pB, vB.b, c1, 0, 0, 0);
    c2 = __builtin_amdgcn_mfma_f32_16x16x32_f16(pB, vB.c, c2, 0, 0, 0);
    c3 = __builtin_amdgcn_mfma_f32_16x16x32_f16(pB, vB.d, c3, 0, 0, 0);
    __builtin_amdgcn_s_setprio(0);
    if (kc + 3 < 32) { pB = ldP(kc + 3); vB = ldV(kc + 3); }
  }
  __syncthreads();           // P region free -> reuse as f32 ctx stage

  // ===== ctx: stage to LDS, then contiguous 1KB/row sweeps =====
  float* sf = (float*)s_;    // [32][256] f32 (32KB)
#pragma unroll
  for (int j = 0; j < 4; ++j) {
    const int row = wr * 16 + lg * 4 + j;
    sf[row * 256 + wc * 64 + l15]      = c0[j];
    sf[row * 256 + wc * 64 + 16 + l15] = c1[j];
    sf[row * 256 + wc * 64 + 32 + l15] = c2[j];
    sf[row * 256 + wc * 64 + 48 + l15] = c3[j];
  }
  __syncthreads();
#pragma unroll
  for (int rr = 0; rr < 4; ++rr) {
    const int r = r0 + rr;
    f32x4 v = *(const f32x4*)(sf + r * 256 + lane * 4);
    const float inv = iv[rr];
    v[0] *= inv; v[1] *= inv; v[2] *= inv; v[3] *= inv;
    *(f32x4*)(CTX + (size_t)r * kDv + lane * 4) = v;
  }
}

}  // namespace

extern "C" void kernel_launch(void* const* d_in, const int* in_sizes, int n_in,
                              void* d_out, int out_size, void* d_ws, size_t ws_size,
                              hipStream_t stream) {
  const float* q = (const float*)d_in[0];
  const float* k = (const float*)d_in[1];
  const float* v = (const float*)d_in[2];
  const float* m = (const float*)d_in[3];
  float* out = (float*)d_out;
  (void)in_sizes; (void)n_in; (void)out_size; (void)ws_size;

  _Float16* k16 = (_Float16*)((char*)d_ws + kWsK);
  _Float16* vt  = (_Float16*)((char*)d_ws + kWsV);
  float*    inv = (float*)((char*)d_ws + kWsInv);

  hipLaunchKernelGGL(cvt_k, dim3(kB * kTk * kD / (256 * 8)), dim3(256), 0, stream,
                     k, k16);
  hipLaunchKernelGGL(trans_v, dim3(kB * 64), dim3(256), 0, stream, v, vt);
  hipLaunchKernelGGL(k1_logits, dim3(2048), dim3(512), 0, stream,
                     q, k16, m, out, inv);
  hipLaunchKernelGGL(k2_pv, dim3(2048), dim3(512), 0, stream, vt, inv, out);
}